// Round 2
// baseline (333.871 us; speedup 1.0000x reference)
//
#include <hip/hip_runtime.h>
#include <hip/hip_cooperative_groups.h>

namespace cg = cooperative_groups;

// Problem constants
#define Bn  16
#define Ln  224
#define K1n 8192
#define Pn  16
#define NCHUNK 16       // k-chunks per batch (512 k each)
#define RG  16          // rows per software-pipeline group in phase A
#define NG  (Ln / RG)   // 14 groups, even -> clean 2-group unroll

// ws layout (floats):
//   ws_sum : [Bn][NCHUNK][Pn]   per-block partial sums
//   ws_max : [Bn][NCHUNK][Pn]   per-block partial maxes
//   ws_mid : [Bn][Pn]           h3 at k = K1/2
// Every slot unconditionally written by exactly one block -> no zeroing,
// no atomics, safe under the harness's 0xAA ws poison.

// ---------------------------------------------------------------------------
// Fused cooperative kernel. Grid: 256 blocks (16 per b), 512 threads.
// Phase A (per-(b,k) h3 stats):
//   - one k per thread, 2 KiB contiguous per row visit per block
//   - copy-free A/B double-buffered 16-row prefetch (no v_mov shuffle)
//   - w3c rows via wave-uniform index -> SGPR operand FMAs
// a/d2 loads for phase B are issued BEFORE the grid sync (latency hides
// under the barrier). Grid-wide sync via cooperative groups, then
// Phase B (reduce partials + finalize + out = h4 + w3_w@(a-d2)).
// ---------------------------------------------------------------------------
__global__ __launch_bounds__(512, 1) void k_fused(
    const float* __restrict__ y,      // [B, L, K1] f32
    const float* __restrict__ w3c,    // [1, L, P]  f32
    const float* __restrict__ sigma,  // [1]        f32
    const float* __restrict__ a,      // [B, P, K1] f32
    const float* __restrict__ d2,     // [B, P, K1] f32
    const float* __restrict__ w3w,    // [P, P] f32
    const float* __restrict__ b3w,    // [P, P] f32
    const float* __restrict__ caw,    // [2, P] f32
    float* __restrict__ ws_sum,
    float* __restrict__ ws_max,
    float* __restrict__ ws_mid,
    float* __restrict__ out)          // [B, P, K1] f32
{
    __shared__ float s_csq_part[32][Pn];
    __shared__ float s_csq[Pn];
    __shared__ float s_part_s[8][Pn];
    __shared__ float s_part_m[8][Pn];
    __shared__ float s_red_s[16][Pn];   // phase B: 16 chunks x 16 p
    __shared__ float s_red_m[16][Pn];
    __shared__ float s_avg[Pn], s_mx[Pn], s_mid[Pn], s_h4[Pn];
    __shared__ float s_t[2];

    const int tid   = threadIdx.x;
    const int lane  = tid & 63;
    const int wv    = tid >> 6;          // 0..7
    const int b     = blockIdx.x >> 4;   // 16 blocks per batch
    const int chunk = blockIdx.x & 15;

    // ---------------- Phase A: h3 stats over this block's 512 k ----------
    // c_sq[p] = sum_l w3c[l][p]^2 — cooperative prologue (512 thr: 32 subs)
    {
        const int p   = tid & 15;
        const int sub = tid >> 4;        // 0..31
        float cs = 0.f;
        for (int l = sub; l < Ln; l += 32) {
            float v = w3c[l * Pn + p];
            cs = fmaf(v, v, cs);
        }
        s_csq_part[sub][p] = cs;
    }
    __syncthreads();
    if (tid < Pn) {
        float cs = 0.f;
#pragma unroll
        for (int s = 0; s < 32; ++s) cs += s_csq_part[s][tid];
        s_csq[tid] = cs;
    }
    __syncthreads();

    float cross[Pn];
#pragma unroll
    for (int p = 0; p < Pn; ++p) cross[p] = 0.f;
    float ysq = 0.f;

    // one k-column per thread: contiguous 2 KiB per row across the block
    const float* yp = y + (size_t)b * Ln * K1n + (chunk << 9) + tid;

    // Copy-free A/B double-buffered 16-row pipeline, 2-group unroll (NG even)
    float vA[RG], vB[RG];
#pragma unroll
    for (int j = 0; j < RG; ++j) vA[j] = yp[(size_t)j * K1n];
#pragma unroll
    for (int j = 0; j < RG; ++j) vB[j] = yp[(size_t)(RG + j) * K1n];

    for (int g = 0; g < NG; g += 2) {
        // consume A (group g), then refill A with group g+2
        {
            const float* wrow = w3c + (size_t)g * RG * Pn;
#pragma unroll
            for (int j = 0; j < RG; ++j) {
                ysq = fmaf(vA[j], vA[j], ysq);
#pragma unroll
                for (int p = 0; p < Pn; ++p)
                    cross[p] = fmaf(vA[j], wrow[j * Pn + p], cross[p]);
            }
        }
        if (g + 2 < NG) {
#pragma unroll
            for (int j = 0; j < RG; ++j)
                vA[j] = yp[(size_t)((g + 2) * RG + j) * K1n];
        }
        // consume B (group g+1), then refill B with group g+3
        {
            const float* wrow = w3c + (size_t)(g + 1) * RG * Pn;
#pragma unroll
            for (int j = 0; j < RG; ++j) {
                ysq = fmaf(vB[j], vB[j], ysq);
#pragma unroll
                for (int p = 0; p < Pn; ++p)
                    cross[p] = fmaf(vB[j], wrow[j * Pn + p], cross[p]);
            }
        }
        if (g + 3 < NG) {
#pragma unroll
            for (int j = 0; j < RG; ++j)
                vB[j] = yp[(size_t)((g + 3) * RG + j) * K1n];
        }
    }

    const float sg = sigma[0];
    const float nh = -0.5f / (sg * sg);

    float h3[Pn];
#pragma unroll
    for (int p = 0; p < Pn; ++p) {
        float d = fmaxf(ysq + s_csq[p] - 2.f * cross[p], 0.f);
        h3[p] = __expf(d * nh);
    }

    // mid = h3[b, p, K1/2] : k == 4096 -> chunk == 8, tid == 0
    if (chunk == 8 && tid == 0) {
#pragma unroll
        for (int p = 0; p < Pn; ++p) ws_mid[b * Pn + p] = h3[p];
    }

    // Wave-level reduce (sum & max) per p, then cross-wave via LDS (8 waves)
#pragma unroll
    for (int p = 0; p < Pn; ++p) {
        float s = h3[p];
        float m = h3[p];
#pragma unroll
        for (int off = 32; off > 0; off >>= 1) {
            s += __shfl_down(s, off, 64);
            m = fmaxf(m, __shfl_down(m, off, 64));
        }
        if (lane == 0) { s_part_s[wv][p] = s; s_part_m[wv][p] = m; }
    }
    __syncthreads();
    if (tid < Pn) {
        float s = 0.f, m = -1.f;
#pragma unroll
        for (int w = 0; w < 8; ++w) {
            s += s_part_s[w][tid];
            m = fmaxf(m, s_part_m[w][tid]);
        }
        const int base = (b * NCHUNK + chunk) * Pn + tid;
        ws_sum[base] = s;
        ws_max[base] = m;
    }

    // ---------------- Phase B prefetch + grid-wide sync -------------------
    // a/d2 loads don't depend on phase A: issue them now so HBM latency
    // hides under the grid barrier.
    const int kb = chunk << 9;   // 512 k per block, 1 per thread
    const float* ap = a  + (size_t)b * Pn * K1n + kb + tid;
    const float* dp = d2 + (size_t)b * Pn * K1n + kb + tid;
    float av[Pn], dv[Pn];
#pragma unroll
    for (int q = 0; q < Pn; ++q) av[q] = ap[(size_t)q * K1n];
#pragma unroll
    for (int q = 0; q < Pn; ++q) dv[q] = dp[(size_t)q * K1n];

    __threadfence();            // make ws writes visible device-wide
    cg::this_grid().sync();     // all partials ready

    // ---------------- Phase B: reduce partials + finalize + out ----------
    if (tid < 256) {
        const int p   = tid & 15;
        const int grp = tid >> 4;          // 0..15
        const int i0  = (b * NCHUNK + grp) * Pn + p;
        s_red_s[grp][p] = ws_sum[i0];
        s_red_m[grp][p] = ws_max[i0];
    }
    __syncthreads();
    if (tid < Pn) {
        float s = 0.f, m = -1.f;
#pragma unroll
        for (int g = 0; g < 16; ++g) {
            s += s_red_s[g][tid];
            m = fmaxf(m, s_red_m[g][tid]);
        }
        s_avg[tid] = s * (1.f / (float)K1n);
        s_mx[tid]  = m;
        s_mid[tid] = ws_mid[b * Pn + tid];
    }
    __syncthreads();

    if (tid < 2) {
        float t1 = 0.f, t2 = 0.f;
        for (int p = 0; p < Pn; ++p) {
            float cw = caw[tid * Pn + p];
            t1 = fmaf(cw, s_avg[p], t1);
            t2 = fmaf(cw, s_mx[p],  t2);
        }
        t1 = (t1 > 0.f) ? t1 : 0.01f * t1;   // leaky_relu
        t2 = (t2 > 0.f) ? t2 : 0.01f * t2;
        s_t[tid] = t1 + t2;
    }
    __syncthreads();

    if (tid < Pn) {
        float t0 = s_t[0], u1 = s_t[1];
        float mt = fmaxf(t0, u1);
        float e0 = __expf(t0 - mt), e1 = __expf(u1 - mt);
        float inv = 1.f / (e0 + e1);
        s_red_s[0][tid] = (e0 * inv) * s_mid[tid] + (e1 * inv) * s_avg[tid];
    }
    __syncthreads();

    if (tid < Pn) {
        float h = 0.f;
        for (int q = 0; q < Pn; ++q) h = fmaf(b3w[tid * Pn + q], s_red_s[0][q], h);
        s_h4[tid] = h;
    }
    __syncthreads();

    // out[b,p,k] = h4[p] + w3_w[p,:]·(a-d2)[b,:,k] ; w3w via SGPR (uniform)
    float diff[Pn];
#pragma unroll
    for (int q = 0; q < Pn; ++q) diff[q] = av[q] - dv[q];

    float* op = out + (size_t)b * Pn * K1n + kb + tid;
#pragma unroll
    for (int p = 0; p < Pn; ++p) {
        float h2 = s_h4[p];
#pragma unroll
        for (int q = 0; q < Pn; ++q)
            h2 = fmaf(w3w[p * Pn + q], diff[q], h2);
        op[(size_t)p * K1n] = h2;
    }
}

// ---------------------------------------------------------------------------
extern "C" void kernel_launch(void* const* d_in, const int* in_sizes, int n_in,
                              void* d_out, int out_size, void* d_ws, size_t ws_size,
                              hipStream_t stream) {
    const float* a     = (const float*)d_in[0];
    const float* d2    = (const float*)d_in[1];
    const float* y     = (const float*)d_in[2];
    const float* w3w   = (const float*)d_in[3];
    const float* b3w   = (const float*)d_in[4];
    const float* w3c   = (const float*)d_in[5];
    const float* sigma = (const float*)d_in[6];
    const float* caw   = (const float*)d_in[7];

    float* ws_sum = (float*)d_ws;
    float* ws_max = ws_sum + Bn * NCHUNK * Pn;
    float* ws_mid = ws_max + Bn * NCHUNK * Pn;
    float* outp   = (float*)d_out;

    void* args[] = {
        (void*)&y, (void*)&w3c, (void*)&sigma,
        (void*)&a, (void*)&d2, (void*)&w3w, (void*)&b3w, (void*)&caw,
        (void*)&ws_sum, (void*)&ws_max, (void*)&ws_mid, (void*)&outp
    };
    hipLaunchCooperativeKernel((const void*)k_fused,
                               dim3(Bn * NCHUNK), dim3(512),
                               args, 0, stream);
}

// Round 3
// 200.107 us; speedup vs baseline: 1.6685x; 1.6685x over previous
//
#include <hip/hip_runtime.h>

// Problem constants
#define Bn  16
#define Ln  224
#define K1n 8192
#define Pn  16
#define NCHUNK 16   // k-chunks per batch (512 k each)
#define RG  16      // rows per software-pipeline group in k_stats
#define NG  (Ln / RG)   // 14 groups, exact

// ws layout (floats):
//   ws_sum : [Bn][NCHUNK][Pn]   per-block partial sums
//   ws_max : [Bn][NCHUNK][Pn]   per-block partial maxes
//   ws_mid : [Bn][Pn]           h3 at k = K1/2
// Every slot unconditionally written by exactly one block -> no zeroing,
// no atomics, safe under the harness's 0xAA ws poison.

// ---------------------------------------------------------------------------
// Kernel 1: per-(b,k) compute h3[p]; per-block reduce sum/max over its 512 k.
// Grid: 256 blocks (16 per b), 512 threads, ONE k per thread (float loads).
// Identical to the round-1 (211.8 us) version EXCEPT: y is loaded with
// __builtin_nontemporal_load. Theory: the y stream is L3-resident and the
// kernel plateaus on Infinity-Cache service bandwidth for 256B-granular
// strided requests; nt steers the stream at the (95%-idle) HBM path and
// avoids cache-allocate overhead. Single-variable experiment vs round 1.
// ---------------------------------------------------------------------------
__global__ __launch_bounds__(512, 2) void k_stats(
    const float* __restrict__ y,      // [B, L, K1] f32
    const float* __restrict__ w3c,    // [1, L, P]  f32
    const float* __restrict__ sigma,  // [1]        f32
    float* __restrict__ ws_sum,
    float* __restrict__ ws_max,
    float* __restrict__ ws_mid)
{
    __shared__ float s_csq_part[32][Pn];
    __shared__ float s_csq[Pn];
    __shared__ float s_part_s[8][Pn];
    __shared__ float s_part_m[8][Pn];

    const int tid   = threadIdx.x;
    const int lane  = tid & 63;
    const int wv    = tid >> 6;          // 0..7
    const int b     = blockIdx.x >> 4;   // 16 blocks per batch
    const int chunk = blockIdx.x & 15;

    // c_sq[p] = sum_l w3c[l][p]^2 — cooperative prologue (512 thr: 32 subs)
    {
        const int p   = tid & 15;
        const int sub = tid >> 4;        // 0..31
        float cs = 0.f;
        for (int l = sub; l < Ln; l += 32) {
            float v = w3c[l * Pn + p];
            cs = fmaf(v, v, cs);
        }
        s_csq_part[sub][p] = cs;
    }
    __syncthreads();
    if (tid < Pn) {
        float cs = 0.f;
#pragma unroll
        for (int s = 0; s < 32; ++s) cs += s_csq_part[s][tid];
        s_csq[tid] = cs;
    }
    __syncthreads();

    float cross[Pn];
#pragma unroll
    for (int p = 0; p < Pn; ++p) cross[p] = 0.f;
    float ysq = 0.f;

    // one k-column per thread: contiguous 2 KiB per row across the block
    const float* yp = y + (size_t)b * Ln * K1n + (chunk << 9) + tid;

    // 16-row software pipeline (double-buffered), nontemporal y loads
    float v[RG], vn[RG];
#pragma unroll
    for (int j = 0; j < RG; ++j)
        v[j] = __builtin_nontemporal_load(yp + (size_t)j * K1n);

    for (int g = 0; g < NG; ++g) {
        if (g < NG - 1) {
#pragma unroll
            for (int j = 0; j < RG; ++j)
                vn[j] = __builtin_nontemporal_load(
                            yp + (size_t)((g + 1) * RG + j) * K1n);
        }
        // rows g*RG .. g*RG+15; w3c access is wave-uniform -> SGPR broadcast
        const float* wrow = w3c + (size_t)g * RG * Pn;
#pragma unroll
        for (int j = 0; j < RG; ++j) {
            ysq = fmaf(v[j], v[j], ysq);
#pragma unroll
            for (int p = 0; p < Pn; ++p)
                cross[p] = fmaf(v[j], wrow[j * Pn + p], cross[p]);
        }
        if (g < NG - 1) {
#pragma unroll
            for (int j = 0; j < RG; ++j) v[j] = vn[j];
        }
    }

    const float sg = sigma[0];
    const float nh = -0.5f / (sg * sg);

    float h3[Pn];
#pragma unroll
    for (int p = 0; p < Pn; ++p) {
        float d = fmaxf(ysq + s_csq[p] - 2.f * cross[p], 0.f);
        h3[p] = __expf(d * nh);
    }

    // mid = h3[b, p, K1/2] : k == 4096 -> chunk == 8, tid == 0
    if (chunk == 8 && tid == 0) {
#pragma unroll
        for (int p = 0; p < Pn; ++p) ws_mid[b * Pn + p] = h3[p];
    }

    // Wave-level reduce (sum & max) per p, then cross-wave via LDS (8 waves)
#pragma unroll
    for (int p = 0; p < Pn; ++p) {
        float s = h3[p];
        float m = h3[p];
#pragma unroll
        for (int off = 32; off > 0; off >>= 1) {
            s += __shfl_down(s, off, 64);
            m = fmaxf(m, __shfl_down(m, off, 64));
        }
        if (lane == 0) { s_part_s[wv][p] = s; s_part_m[wv][p] = m; }
    }
    __syncthreads();
    if (tid < Pn) {
        float s = 0.f, m = -1.f;
#pragma unroll
        for (int w = 0; w < 8; ++w) {
            s += s_part_s[w][tid];
            m = fmaxf(m, s_part_m[w][tid]);
        }
        const int base = (b * NCHUNK + chunk) * Pn + tid;
        ws_sum[base] = s;
        ws_max[base] = m;
    }
}

// ---------------------------------------------------------------------------
// Kernel 2: reduce partials + tiny finalize (h4[b,p]) + out = h4 + w3_w@(a-d2).
// Grid: 256 blocks (16 per b), 512 threads, one k per thread. 2 waves/SIMD.
// Byte-identical to round 1 (control arm of this experiment).
// ---------------------------------------------------------------------------
__global__ __launch_bounds__(512, 2) void k_out(
    const float* __restrict__ a,      // [B, P, K1] f32
    const float* __restrict__ d2,    // [B, P, K1] f32
    const float* __restrict__ w3w,    // [P, P] f32
    const float* __restrict__ b3w,    // [P, P] f32
    const float* __restrict__ caw,    // [2, P] f32
    const float* __restrict__ ws_sum,
    const float* __restrict__ ws_max,
    const float* __restrict__ ws_mid,
    float* __restrict__ out)          // [B, P, K1] f32
{
    __shared__ float s_red_s[16][Pn];   // 16 chunks x 16 p ; [0] reused for comb
    __shared__ float s_red_m[16][Pn];
    __shared__ float s_avg[Pn], s_mx[Pn], s_mid[Pn], s_h4[Pn];
    __shared__ float s_t[2];

    const int tid = threadIdx.x;
    const int b   = blockIdx.x >> 4;
    const int kb  = (blockIdx.x & 15) << 9;   // 512 k per block, 1 per thread

    // Issue the big streaming loads first — in flight across the finalize.
    const float* ap = a  + (size_t)b * Pn * K1n + kb + tid;
    const float* dp = d2 + (size_t)b * Pn * K1n + kb + tid;
    float av[Pn], dv[Pn];
#pragma unroll
    for (int q = 0; q < Pn; ++q) av[q] = ap[(size_t)q * K1n];
#pragma unroll
    for (int q = 0; q < Pn; ++q) dv[q] = dp[(size_t)q * K1n];

    // Parallel partial-load: threads 0..255 fetch the 16x16 ws partials
    if (tid < 256) {
        const int p   = tid & 15;
        const int grp = tid >> 4;          // 0..15
        const int i0  = (b * NCHUNK + grp) * Pn + p;
        s_red_s[grp][p] = ws_sum[i0];
        s_red_m[grp][p] = ws_max[i0];
    }
    __syncthreads();
    if (tid < Pn) {
        float s = 0.f, m = -1.f;
#pragma unroll
        for (int g = 0; g < 16; ++g) {
            s += s_red_s[g][tid];
            m = fmaxf(m, s_red_m[g][tid]);
        }
        s_avg[tid] = s * (1.f / (float)K1n);
        s_mx[tid]  = m;
        s_mid[tid] = ws_mid[b * Pn + tid];
    }
    __syncthreads();

    if (tid < 2) {
        float t1 = 0.f, t2 = 0.f;
        for (int p = 0; p < Pn; ++p) {
            float cw = caw[tid * Pn + p];
            t1 = fmaf(cw, s_avg[p], t1);
            t2 = fmaf(cw, s_mx[p],  t2);
        }
        t1 = (t1 > 0.f) ? t1 : 0.01f * t1;   // leaky_relu
        t2 = (t2 > 0.f) ? t2 : 0.01f * t2;
        s_t[tid] = t1 + t2;
    }
    __syncthreads();

    if (tid < Pn) {
        float t0 = s_t[0], u1 = s_t[1];
        float mt = fmaxf(t0, u1);
        float e0 = __expf(t0 - mt), e1 = __expf(u1 - mt);
        float inv = 1.f / (e0 + e1);
        s_red_s[0][tid] = (e0 * inv) * s_mid[tid] + (e1 * inv) * s_avg[tid];
    }
    __syncthreads();

    if (tid < Pn) {
        float h = 0.f;
        for (int q = 0; q < Pn; ++q) h = fmaf(b3w[tid * Pn + q], s_red_s[0][q], h);
        s_h4[tid] = h;
    }
    __syncthreads();

    // out[b,p,k] = h4[p] + w3_w[p,:]·(a-d2)[b,:,k] ; w3w via SGPR (uniform)
    float diff[Pn];
#pragma unroll
    for (int q = 0; q < Pn; ++q) diff[q] = av[q] - dv[q];

    float* op = out + (size_t)b * Pn * K1n + kb + tid;
#pragma unroll
    for (int p = 0; p < Pn; ++p) {
        float h2 = s_h4[p];
#pragma unroll
        for (int q = 0; q < Pn; ++q)
            h2 = fmaf(w3w[p * Pn + q], diff[q], h2);
        op[(size_t)p * K1n] = h2;
    }
}

// ---------------------------------------------------------------------------
extern "C" void kernel_launch(void* const* d_in, const int* in_sizes, int n_in,
                              void* d_out, int out_size, void* d_ws, size_t ws_size,
                              hipStream_t stream) {
    const float* a     = (const float*)d_in[0];
    const float* d2    = (const float*)d_in[1];
    const float* y     = (const float*)d_in[2];
    const float* w3w   = (const float*)d_in[3];
    const float* b3w   = (const float*)d_in[4];
    const float* w3c   = (const float*)d_in[5];
    const float* sigma = (const float*)d_in[6];
    const float* caw   = (const float*)d_in[7];

    float* ws_sum = (float*)d_ws;
    float* ws_max = ws_sum + Bn * NCHUNK * Pn;
    float* ws_mid = ws_max + Bn * NCHUNK * Pn;

    k_stats<<<dim3(Bn * NCHUNK), dim3(512), 0, stream>>>(
        y, w3c, sigma, ws_sum, ws_max, ws_mid);

    k_out<<<dim3(Bn * NCHUNK), dim3(512), 0, stream>>>(
        a, d2, w3w, b3w, caw, ws_sum, ws_max, ws_mid, (float*)d_out);
}